// Round 4
// baseline (304.078 us; speedup 1.0000x reference)
//
#include <hip/hip_runtime.h>
#include <hip/hip_fp16.h>

#define N_PTS 100000
#define KSZ 9
#define C_IN 24
#define C_HID 144
#define C_OUT 24
#define EPSV 1e-5f
#define CPTS 7
#define NCH ((N_PTS + CPTS - 1) / CPTS)          // 14286

// ---- workspace layout (byte offsets) ----
// x1n: fp16 (N+1) x 144   [0, 28,800,288)
// x2 : fp16  N    x 144   [28,800,512, 57,600,512)
// st : f32 stats          [57,600,512, +4096)
// y3 : f32  N x 24        aliases x1n (x1n dead after conv)
#define X1N_B 0ull
#define X2_B  28800512ull
#define ST_B  57600512ull
#define Y3_B  0ull

#define MU1_F  0
#define M1_F   32
#define SUM2_F 640
#define SQ2_F  800
#define SUM3_F 960
#define SQ3_F  992

typedef float f2v __attribute__((ext_vector_type(2)));

__device__ inline float4 f4z() { return make_float4(0.f, 0.f, 0.f, 0.f); }
__device__ inline float4 f4_fma_s(float s, float4 b, float4 c) {
    return make_float4(fmaf(s, b.x, c.x), fmaf(s, b.y, c.y),
                       fmaf(s, b.z, c.z), fmaf(s, b.w, c.w));
}
__device__ inline float clamp6(float x) { return fminf(fmaxf(x, 0.f), 6.f); }

// ---- K1: feats moments straight from global (round-1 verified)
__global__ void k_moments(const float* __restrict__ feats, char* __restrict__ wsb) {
    int t = threadIdx.x;  // blockDim 640, 600 active
    float* STF = (float*)(wsb + ST_B);
    int len = (N_PTS + gridDim.x - 1) / gridDim.x;
    int r0 = blockIdx.x * len;
    int r1 = min(r0 + len, N_PTS);
    if (t >= 600) return;
    float a = 0.f;
    if (t < 576) {
        int i = t / 24, j = t % 24;
#pragma unroll 4
        for (int r = r0; r < r1; r++)
            a = fmaf(feats[(size_t)r * 24 + i], feats[(size_t)r * 24 + j], a);
        atomicAdd(&STF[M1_F + t], a);
    } else {
        int k = t - 576;
#pragma unroll 4
        for (int r = r0; r < r1; r++) a += feats[(size_t)r * 24 + k];
        atomicAdd(&STF[MU1_F + k], a);
    }
}

// ---- K2: GEMM1 (N,24)@(24,144) + BN1 + relu6 -> x1n fp16 (round-1 verified)
__global__ void __launch_bounds__(576, 5)
k_gemm1(const float* __restrict__ feats, const float* __restrict__ w1,
        const float* __restrict__ g1, const float* __restrict__ b1,
        char* __restrict__ wsb) {
    __shared__ float scs[C_HID], shs[C_HID];
    float* STF = (float*)(wsb + ST_B);
    int t = threadIdx.x;
    if (t < C_HID) {
        float wc[C_IN];
#pragma unroll
        for (int k = 0; k < C_IN; k++) wc[k] = w1[k * C_HID + t];
        const float invN = 1.f / (float)N_PTS;
        float mean = 0.f;
#pragma unroll
        for (int k = 0; k < C_IN; k++) mean = fmaf(STF[MU1_F + k], wc[k], mean);
        mean *= invN;
        float e2 = 0.f;
        for (int i = 0; i < C_IN; i++) {
            float s = 0.f;
#pragma unroll
            for (int j = 0; j < C_IN; j++) s = fmaf(STF[M1_F + i * 24 + j], wc[j], s);
            e2 = fmaf(wc[i], s, e2);
        }
        e2 *= invN;
        float var = e2 - mean * mean;
        float s1 = g1[t] * rsqrtf(var + EPSV);
        scs[t] = s1;
        shs[t] = b1[t] - mean * s1;
    }
    __syncthreads();
    int c = t % C_HID, pg = t / C_HID;  // pg in [0,4)
    float sc = scs[c];
    float sh = shs[c];
    float wreg[C_IN];
#pragma unroll
    for (int k = 0; k < C_IN; k++) wreg[k] = w1[k * C_HID + c] * sc;
    __half* x1h = (__half*)(wsb + X1N_B);
    for (int p = blockIdx.x * 4 + pg; p < N_PTS; p += gridDim.x * 4) {
        const float4* fr = (const float4*)(feats + (size_t)p * C_IN);
        float acc = sh;
#pragma unroll
        for (int q = 0; q < 6; q++) {
            float4 f = fr[q];
            acc = fmaf(f.x, wreg[4 * q + 0], acc);
            acc = fmaf(f.y, wreg[4 * q + 1], acc);
            acc = fmaf(f.z, wreg[4 * q + 2], acc);
            acc = fmaf(f.w, wreg[4 * q + 3], acc);
        }
        x1h[(size_t)p * C_HID + c] = __float2half_rn(clamp6(acc));
    }
}

// ---- K3: channelwise conv, 4 fp16 ch/lane, weights in VGPRs, 2-deep pipeline
__device__ inline void cissue(int ch, int pt, bool act, const int* __restrict__ in_idx,
                              const __half* __restrict__ x1h, int c0, f2v vv[KSZ]) {
    int p = ch * CPTS + pt;
    bool ok = act && ch < NCH && p < N_PTS;
    int pcl = ok ? p : 0;
    int idxs[KSZ];
#pragma unroll
    for (int k = 0; k < KSZ; k++) idxs[k] = ok ? in_idx[k * N_PTS + pcl] : N_PTS;
#pragma unroll
    for (int k = 0; k < KSZ; k++)
        vv[k] = *(const f2v*)(x1h + (size_t)idxs[k] * C_HID + c0);
}

__device__ inline void ccomp(int ch, int pt, bool act, const float4 wr[KSZ], int c0,
                             __half* __restrict__ x2h, const f2v vv[KSZ],
                             float rs[4], float rq[4]) {
    int p = ch * CPTS + pt;
    bool ok = act && p < N_PTS;
    float a0 = 0.f, a1 = 0.f, a2 = 0.f, a3 = 0.f;
#pragma unroll
    for (int k = 0; k < KSZ; k++) {
        union { f2v f; __half2 h[2]; } u;
        u.f = vv[k];
        float2 lo = __half22float2(u.h[0]);
        float2 hi = __half22float2(u.h[1]);
        a0 = fmaf(wr[k].x, lo.x, a0);
        a1 = fmaf(wr[k].y, lo.y, a1);
        a2 = fmaf(wr[k].z, hi.x, a2);
        a3 = fmaf(wr[k].w, hi.y, a3);
    }
    if (ok) {
        union { f2v f; __half2 h[2]; } o;
        o.h[0] = __float22half2_rn(make_float2(a0, a1));
        o.h[1] = __float22half2_rn(make_float2(a2, a3));
        __builtin_nontemporal_store(o.f, (f2v*)(x2h + (size_t)p * C_HID + c0));
    }
    // !ok lanes saw the zero sentinel -> a*==0 -> harmless for stats
    rs[0] += a0; rs[1] += a1; rs[2] += a2; rs[3] += a3;
    rq[0] = fmaf(a0, a0, rq[0]); rq[1] = fmaf(a1, a1, rq[1]);
    rq[2] = fmaf(a2, a2, rq[2]); rq[3] = fmaf(a3, a3, rq[3]);
}

__global__ void __launch_bounds__(256, 4)
k_conv(const float* __restrict__ w2, const int* __restrict__ in_idx,
       char* __restrict__ wsb) {
    __shared__ float lsum[C_HID], lsq[C_HID];
    float* STF = (float*)(wsb + ST_B);
    int t = threadIdx.x;
    if (t < C_HID) { lsum[t] = 0.f; lsq[t] = 0.f; }
    bool act = t < 252;                       // 7 points x 36 lanes
    int pt = t / 36, g = t % 36, c0 = g * 4;
    float4 wr[KSZ];                           // per-lane weights in registers
#pragma unroll
    for (int k = 0; k < KSZ; k++) wr[k] = *(const float4*)(w2 + k * C_HID + c0);
    __syncthreads();
    const __half* x1h = (const __half*)(wsb + X1N_B);
    __half* x2h = (__half*)(wsb + X2_B);
    float rs[4] = {0.f, 0.f, 0.f, 0.f}, rq[4] = {0.f, 0.f, 0.f, 0.f};
    f2v va[KSZ], vb[KSZ];
    int chA = (int)blockIdx.x, chB = chA + (int)gridDim.x;
    cissue(chA, pt, act, in_idx, x1h, c0, va);
    while (chA < NCH) {
        cissue(chB, pt, act, in_idx, x1h, c0, vb);
        ccomp(chA, pt, act, wr, c0, x2h, va, rs, rq);
        chA = chB + (int)gridDim.x;
        if (chB >= NCH) break;
        cissue(chA, pt, act, in_idx, x1h, c0, va);
        ccomp(chB, pt, act, wr, c0, x2h, vb, rs, rq);
        chB = chA + (int)gridDim.x;
    }
    if (act) {
#pragma unroll
        for (int j = 0; j < 4; j++) {
            atomicAdd(&lsum[c0 + j], rs[j]);
            atomicAdd(&lsq[c0 + j], rq[j]);
        }
    }
    __syncthreads();
    if (t < C_HID) {
        atomicAdd(&STF[SUM2_F + t], lsum[t]);
        atomicAdd(&STF[SQ2_F + t], lsq[t]);
    }
}

// ---- K4: GEMM2 (N,144)@(144,24), BN2+relu6 on the fly, fused fin2 prologue
//          + fused BN3 stats (wave butterfly + block stage)
__global__ void k_gemm2(const float* __restrict__ w3, const float* __restrict__ g2,
                        const float* __restrict__ b2, char* __restrict__ wsb) {
    __shared__ float4 w3s[C_HID * 6];
    __shared__ float4 sc2v[C_HID / 4], sh2v[C_HID / 4];
    __shared__ float red[192];
    float* STF = (float*)(wsb + ST_B);
    int t = threadIdx.x;
    for (int e = t; e < C_HID * 6; e += 256) w3s[e] = ((const float4*)w3)[e];
    if (t < C_HID) {
        const float invN = 1.f / (float)N_PTS;
        float mean = STF[SUM2_F + t] * invN;
        float var = STF[SQ2_F + t] * invN - mean * mean;
        float s = g2[t] * rsqrtf(var + EPSV);
        ((float*)sc2v)[t] = s;
        ((float*)sh2v)[t] = b2[t] - mean * s;
    }
    __syncthreads();
    int r = blockIdx.x * 256 + t;
    bool ok = r < N_PTS;
    float4 a[6];
#pragma unroll
    for (int c4 = 0; c4 < 6; c4++) a[c4] = f4z();
    if (ok) {
        const float4* x2v = (const float4*)(wsb + X2_B + (size_t)r * (C_HID * 2));
#pragma unroll 3
        for (int h8 = 0; h8 < 18; h8++) {
            union { float4 f; __half2 h[4]; } u;
            u.f = x2v[h8];
            float4 s0 = sc2v[2 * h8], s1 = sc2v[2 * h8 + 1];
            float4 b0 = sh2v[2 * h8], b1v = sh2v[2 * h8 + 1];
            float2 x0 = __half22float2(u.h[0]);
            float2 x1 = __half22float2(u.h[1]);
            float2 x2 = __half22float2(u.h[2]);
            float2 x3 = __half22float2(u.h[3]);
            float xs[8];
            xs[0] = clamp6(fmaf(x0.x, s0.x, b0.x));
            xs[1] = clamp6(fmaf(x0.y, s0.y, b0.y));
            xs[2] = clamp6(fmaf(x1.x, s0.z, b0.z));
            xs[3] = clamp6(fmaf(x1.y, s0.w, b0.w));
            xs[4] = clamp6(fmaf(x2.x, s1.x, b1v.x));
            xs[5] = clamp6(fmaf(x2.y, s1.y, b1v.y));
            xs[6] = clamp6(fmaf(x3.x, s1.z, b1v.z));
            xs[7] = clamp6(fmaf(x3.y, s1.w, b1v.w));
#pragma unroll
            for (int j = 0; j < 8; j++) {
                int h = h8 * 8 + j;
#pragma unroll
                for (int c4 = 0; c4 < 6; c4++)
                    a[c4] = f4_fma_s(xs[j], w3s[h * 6 + c4], a[c4]);
            }
        }
        float4* y3v = (float4*)(wsb + Y3_B) + (size_t)r * 6;
#pragma unroll
        for (int c4 = 0; c4 < 6; c4++) y3v[c4] = a[c4];
    }
    // fused red3: butterfly per wave, stage, 48 atomics per block
    int wv = t >> 6, ln = t & 63;
#pragma unroll
    for (int c4 = 0; c4 < 6; c4++) {
        float4 s = a[c4];
        float4 q = make_float4(s.x * s.x, s.y * s.y, s.z * s.z, s.w * s.w);
#pragma unroll
        for (int m = 1; m < 64; m <<= 1) {
            s.x += __shfl_xor(s.x, m); s.y += __shfl_xor(s.y, m);
            s.z += __shfl_xor(s.z, m); s.w += __shfl_xor(s.w, m);
            q.x += __shfl_xor(q.x, m); q.y += __shfl_xor(q.y, m);
            q.z += __shfl_xor(q.z, m); q.w += __shfl_xor(q.w, m);
        }
        if (ln == 0) {
            int base = wv * 48 + c4 * 4;
            red[base + 0] = s.x; red[base + 1] = s.y;
            red[base + 2] = s.z; red[base + 3] = s.w;
            red[base + 24 + 0] = q.x; red[base + 24 + 1] = q.y;
            red[base + 24 + 2] = q.z; red[base + 24 + 3] = q.w;
        }
    }
    __syncthreads();
    if (t < 48) {
        float v = red[t] + red[48 + t] + red[96 + t] + red[144 + t];
        if (t < 24) atomicAdd(&STF[SUM3_F + t], v);
        else        atomicAdd(&STF[SQ3_F + t - 24], v);
    }
}

// ---- K5: out = bn3(y3) + feats, fused fin3 prologue (round-1 verified)
__global__ void k_out(const float* __restrict__ feats, const float* __restrict__ g3,
                      const float* __restrict__ b3, const char* __restrict__ wsb,
                      float* __restrict__ out) {
    __shared__ float s3[C_OUT], h3[C_OUT];
    const float* STF = (const float*)(wsb + ST_B);
    int t = threadIdx.x;
    if (t < C_OUT) {
        const float invN = 1.f / (float)N_PTS;
        float mean = STF[SUM3_F + t] * invN;
        float var = STF[SQ3_F + t] * invN - mean * mean;
        float s = g3[t] * rsqrtf(var + EPSV);
        s3[t] = s;
        h3[t] = b3[t] - mean * s;
    }
    __syncthreads();
    int tau = blockIdx.x * 256 + t;
    if (tau >= N_PTS * 6) return;
    int c = (tau % 6) * 4;
    float4 y = ((const float4*)(wsb + Y3_B))[tau];
    float4 f = ((const float4*)feats)[tau];
    float4 o;
    o.x = fmaf(y.x, s3[c + 0], h3[c + 0]) + f.x;
    o.y = fmaf(y.y, s3[c + 1], h3[c + 1]) + f.y;
    o.z = fmaf(y.z, s3[c + 2], h3[c + 2]) + f.z;
    o.w = fmaf(y.w, s3[c + 3], h3[c + 3]) + f.w;
    ((float4*)out)[tau] = o;
}

extern "C" void kernel_launch(void* const* d_in, const int* in_sizes, int n_in,
                              void* d_out, int out_size, void* d_ws, size_t ws_size,
                              hipStream_t stream) {
    const float* feats = (const float*)d_in[0];
    const float* w1 = (const float*)d_in[1];
    const float* g1 = (const float*)d_in[2];
    const float* b1 = (const float*)d_in[3];
    const float* w2 = (const float*)d_in[4];
    const float* g2 = (const float*)d_in[5];
    const float* b2 = (const float*)d_in[6];
    const float* w3 = (const float*)d_in[7];
    const float* g3 = (const float*)d_in[8];
    const float* b3 = (const float*)d_in[9];
    const int* in_idx = (const int*)d_in[10];
    char* wsb = (char*)d_ws;
    float* out = (float*)d_out;

    // stats zero (4KB) + fp16 sentinel row N (288B) via graph-native memset nodes
    (void)hipMemsetAsync(wsb + ST_B, 0, 4096, stream);
    (void)hipMemsetAsync(wsb + (size_t)N_PTS * C_HID * 2, 0, C_HID * 2, stream);

    hipLaunchKernelGGL(k_moments, dim3(256), dim3(640), 0, stream, feats, wsb);
    hipLaunchKernelGGL(k_gemm1, dim3(1024), dim3(576), 0, stream, feats, w1, g1, b1, wsb);
    hipLaunchKernelGGL(k_conv, dim3(2048), dim3(256), 0, stream, w2, in_idx, wsb);
    hipLaunchKernelGGL(k_gemm2, dim3((N_PTS + 255) / 256), dim3(256), 0, stream,
                       w3, g2, b2, wsb);
    hipLaunchKernelGGL(k_out, dim3((N_PTS * 6 + 255) / 256), dim3(256), 0, stream,
                       feats, g3, b3, wsb, out);
}